// Round 1
// baseline (909.369 us; speedup 1.0000x reference)
//
#include <hip/hip_runtime.h>
#include <math.h>

#define N_LOC 32768
#define CONTENT 512
#define ADDR_D 64
#define HID 1024
#define IN_D 256
#define OUT_D 10
#define OVERALL 576
#define GRU_IN 832
#define EPS_C 1e-7f
#define NSTEPS 8

__device__ __forceinline__ float wred(float v) {
    #pragma unroll
    for (int m = 32; m; m >>= 1) v += __shfl_xor(v, m, 64);
    return v;
}
__device__ __forceinline__ float sigm(float x) { return 1.0f / (1.0f + expf(-x)); }

// ---------------- init: addr row norms^2, zero ema + scalar slots ----------------
__global__ __launch_bounds__(256) void k_init(const float* __restrict__ addrRows,
                                              float* __restrict__ addrsq,
                                              float* __restrict__ ema,
                                              float* __restrict__ slots) {
    int tid = threadIdx.x, wid = tid >> 6, lane = tid & 63;
    int gid = blockIdx.x * 256 + tid;
    if (gid < N_LOC) ema[gid] = 0.0f;
    if (gid < 64) slots[gid] = 0.0f;
    for (int i = blockIdx.x * 4 + wid; i < N_LOC; i += gridDim.x * 4) {
        float a = addrRows[(size_t)i * ADDR_D + lane];
        float sq = wred(a * a);
        if (lane == 0) addrsq[i] = sq;
    }
}

// ---------------- small matvecs: erase, cand, query (next step), u_s·h, u_l·h ----------------
__global__ __launch_bounds__(256) void k_small(
    const float* __restrict__ W_e, const float* __restrict__ b_e,
    const float* __restrict__ W_ch, const float* __restrict__ W_ci, const float* __restrict__ b_c,
    const float* __restrict__ W_q, const float* __restrict__ b_q,
    const float* __restrict__ u_s, const float* __restrict__ u_l,
    const float* __restrict__ x, const float* __restrict__ h,
    float* __restrict__ erase, float* __restrict__ cand, float* __restrict__ query,
    float* __restrict__ slots_next, int nErase) {
    int tid = threadIdx.x, wid = tid >> 6, lane = tid & 63;
    int t = blockIdx.x * 4 + wid;
    int nQ0 = 2 * nErase;
    if (t < nErase) {
        const float* row = W_e + (size_t)t * HID;
        float d = 0.0f;
        for (int j = lane; j < HID; j += 64) d += row[j] * h[j];
        d = wred(d);
        if (lane == 0) erase[t] = sigm(d + b_e[t]);
    } else if (t < nQ0) {
        int r = t - nErase;
        const float* row = W_ch + (size_t)r * HID;
        float d = 0.0f;
        for (int j = lane; j < HID; j += 64) d += row[j] * h[j];
        const float* row2 = W_ci + (size_t)r * IN_D;
        for (int j = lane; j < IN_D; j += 64) d += row2[j] * x[j];
        d = wred(d);
        if (lane == 0) cand[r] = fmaxf(d + b_c[r], 0.0f);
    } else if (t < nQ0 + OVERALL) {
        int r = t - nQ0;
        const float* row = W_q + (size_t)r * HID;
        float d = 0.0f;
        for (int j = lane; j < HID; j += 64) d += row[j] * h[j];
        d = wred(d);
        if (lane == 0) {
            float q = d + b_q[r];
            query[r] = q;
            atomicAdd(slots_next + 0, q * q);
        }
    } else if (t == nQ0 + OVERALL) {
        float d = 0.0f;
        for (int j = lane; j < HID; j += 64) d += u_s[j] * h[j];
        d = wred(d);
        if (lane == 0) atomicAdd(slots_next + 1, d);
    } else if (t == nQ0 + OVERALL + 1) {
        float d = 0.0f;
        for (int j = lane; j < HID; j += 64) d += u_l[j] * h[j];
        d = wred(d);
        if (lane == 0) atomicAdd(slots_next + 2, d);
    }
}

// ---------------- pass A: (lazy mem update from prev step) + dots + row norm + sim/ema/s + exp-sum ----------------
__global__ __launch_bounds__(256) void k_passA(
    const float* __restrict__ memIn, float* __restrict__ memOut, int doUpdate,
    const float* __restrict__ addrRows, const float* __restrict__ query,
    const float* __restrict__ w, const float* __restrict__ erase, const float* __restrict__ cand,
    const float* __restrict__ addrsq, float* __restrict__ s, float* __restrict__ ema,
    float* __restrict__ reading, const float* __restrict__ slots,
    const float* __restrict__ b_sh, const float* __restrict__ b_lr,
    float* __restrict__ ssum) {
    int tid = threadIdx.x, wid = tid >> 6, lane = tid & 63;
    // zero the reading accumulator for this step's pass B (consumed by prev step's GRU already)
    if (blockIdx.x == 0) {
        for (int c = tid; c < OVERALL; c += 256) reading[c] = 0.0f;
    }
    float qnorm = sqrtf(slots[0]);
    float bs = slots[1] + b_sh[0];
    float beta = (bs > 20.0f ? bs : log1pf(expf(bs))) + 1.0f;
    float gamma = sigm(slots[2] + b_lr[0]);

    float4 q0 = *(const float4*)(query + 4 * lane);
    float4 q1 = *(const float4*)(query + 256 + 4 * lane);
    float qa = query[512 + lane];
    float4 e0 = {0, 0, 0, 0}, e1 = {0, 0, 0, 0}, c0 = {0, 0, 0, 0}, c1 = {0, 0, 0, 0};
    if (doUpdate) {
        e0 = *(const float4*)(erase + 4 * lane);
        e1 = *(const float4*)(erase + 256 + 4 * lane);
        c0 = *(const float4*)(cand + 4 * lane);
        c1 = *(const float4*)(cand + 256 + 4 * lane);
    }

    float lexp = 0.0f;
    for (int i = blockIdx.x * 4 + wid; i < N_LOC; i += gridDim.x * 4) {
        const float4* mrow = (const float4*)(memIn + (size_t)i * CONTENT);
        float4 m0 = mrow[lane];
        float4 m1 = mrow[64 + lane];
        if (doUpdate) {
            float wi = w[i];
            m0.x = m0.x * (1.0f - wi * e0.x) + wi * c0.x;
            m0.y = m0.y * (1.0f - wi * e0.y) + wi * c0.y;
            m0.z = m0.z * (1.0f - wi * e0.z) + wi * c0.z;
            m0.w = m0.w * (1.0f - wi * e0.w) + wi * c0.w;
            m1.x = m1.x * (1.0f - wi * e1.x) + wi * c1.x;
            m1.y = m1.y * (1.0f - wi * e1.y) + wi * c1.y;
            m1.z = m1.z * (1.0f - wi * e1.z) + wi * c1.z;
            m1.w = m1.w * (1.0f - wi * e1.w) + wi * c1.w;
            float4* orow = (float4*)(memOut + (size_t)i * CONTENT);
            orow[lane] = m0;
            orow[64 + lane] = m1;
        }
        float d = m0.x * q0.x + m0.y * q0.y + m0.z * q0.z + m0.w * q0.w
                + m1.x * q1.x + m1.y * q1.y + m1.z * q1.z + m1.w * q1.w;
        float sq = m0.x * m0.x + m0.y * m0.y + m0.z * m0.z + m0.w * m0.w
                 + m1.x * m1.x + m1.y * m1.y + m1.z * m1.z + m1.w * m1.w;
        float a = addrRows[(size_t)i * ADDR_D + lane];
        d += a * qa;
        d = wred(d);
        sq = wred(sq);
        if (lane == 0) {
            float rn = sqrtf(sq + addrsq[i]);
            float sim = beta * d / (rn * qnorm + EPS_C);
            float eo = ema[i];
            float si = sim - gamma * eo;
            ema[i] = 0.1f * eo + 0.9f * sim;
            s[i] = si;
            lexp += expf(si);
        }
    }
    __shared__ float red[4];
    if (lane == 0) red[wid] = lexp;
    __syncthreads();
    if (tid == 0) atomicAdd(ssum, red[0] + red[1] + red[2] + red[3]);
}

// ---------------- pass B: w = exp(s)/ssum ; reading = full^T @ w ----------------
__global__ __launch_bounds__(256) void k_passB(
    const float* __restrict__ mem, const float* __restrict__ addrRows,
    const float* __restrict__ s, const float* __restrict__ ssum,
    float* __restrict__ w, float* __restrict__ reading) {
    int tid = threadIdx.x, wid = tid >> 6, lane = tid & 63;
    __shared__ float lred[OVERALL];
    for (int c = tid; c < OVERALL; c += 256) lred[c] = 0.0f;
    __syncthreads();
    float inv = 1.0f / ssum[0];
    float4 a0 = {0, 0, 0, 0}, a1 = {0, 0, 0, 0};
    float aa = 0.0f;
    for (int i = blockIdx.x * 4 + wid; i < N_LOC; i += gridDim.x * 4) {
        float wi = expf(s[i]) * inv;
        if (lane == 0) w[i] = wi;
        const float4* mrow = (const float4*)(mem + (size_t)i * CONTENT);
        float4 m0 = mrow[lane];
        float4 m1 = mrow[64 + lane];
        a0.x += wi * m0.x; a0.y += wi * m0.y; a0.z += wi * m0.z; a0.w += wi * m0.w;
        a1.x += wi * m1.x; a1.y += wi * m1.y; a1.z += wi * m1.z; a1.w += wi * m1.w;
        aa += wi * addrRows[(size_t)i * ADDR_D + lane];
    }
    atomicAdd(&lred[4 * lane + 0], a0.x);
    atomicAdd(&lred[4 * lane + 1], a0.y);
    atomicAdd(&lred[4 * lane + 2], a0.z);
    atomicAdd(&lred[4 * lane + 3], a0.w);
    atomicAdd(&lred[256 + 4 * lane + 0], a1.x);
    atomicAdd(&lred[256 + 4 * lane + 1], a1.y);
    atomicAdd(&lred[256 + 4 * lane + 2], a1.z);
    atomicAdd(&lred[256 + 4 * lane + 3], a1.w);
    atomicAdd(&lred[512 + lane], aa);
    __syncthreads();
    for (int c = tid; c < OVERALL; c += 256) atomicAdd(reading + c, lred[c]);
}

// ---------------- GRU: one wave per hidden unit ----------------
__global__ __launch_bounds__(256) void k_gru(
    const float* __restrict__ W_ih, const float* __restrict__ W_hh,
    const float* __restrict__ b_ih, const float* __restrict__ b_hh,
    const float* __restrict__ x, const float* __restrict__ reading,
    const float* __restrict__ hcur, float* __restrict__ hnew) {
    int tid = threadIdx.x, wid = tid >> 6, lane = tid & 63;
    int k = blockIdx.x * 4 + wid;
    if (k >= HID) return;
    float gi0 = 0, gi1 = 0, gi2 = 0, gh0 = 0, gh1 = 0, gh2 = 0;
    for (int j = lane; j < GRU_IN; j += 64) {
        float v = (j < IN_D) ? x[j] : reading[j - IN_D];
        gi0 += W_ih[(size_t)k * GRU_IN + j] * v;
        gi1 += W_ih[(size_t)(k + HID) * GRU_IN + j] * v;
        gi2 += W_ih[(size_t)(k + 2 * HID) * GRU_IN + j] * v;
    }
    for (int j = lane; j < HID; j += 64) {
        float v = hcur[j];
        gh0 += W_hh[(size_t)k * HID + j] * v;
        gh1 += W_hh[(size_t)(k + HID) * HID + j] * v;
        gh2 += W_hh[(size_t)(k + 2 * HID) * HID + j] * v;
    }
    gi0 = wred(gi0); gi1 = wred(gi1); gi2 = wred(gi2);
    gh0 = wred(gh0); gh1 = wred(gh1); gh2 = wred(gh2);
    if (lane == 0) {
        float r = sigm(gi0 + b_ih[k] + gh0 + b_hh[k]);
        float z = sigm(gi1 + b_ih[HID + k] + gh1 + b_hh[HID + k]);
        float n = tanhf(gi2 + b_ih[2 * HID + k] + r * (gh2 + b_hh[2 * HID + k]));
        hnew[k] = (1.0f - z) * n + z * hcur[k];
    }
}

// ---------------- output: copy h, logits + log_softmax ----------------
__global__ __launch_bounds__(256) void k_out(const float* __restrict__ W_o,
                                             const float* __restrict__ b_o,
                                             const float* __restrict__ h,
                                             float* __restrict__ out) {
    int tid = threadIdx.x;
    for (int j = tid; j < HID; j += 256) out[j] = h[j];
    float acc[OUT_D];
    #pragma unroll
    for (int r = 0; r < OUT_D; r++) acc[r] = 0.0f;
    for (int j = tid; j < HID; j += 256) {
        float hj = h[j];
        #pragma unroll
        for (int r = 0; r < OUT_D; r++) acc[r] += W_o[(size_t)r * HID + j] * hj;
    }
    __shared__ float lg[OUT_D];
    if (tid < OUT_D) lg[tid] = 0.0f;
    __syncthreads();
    #pragma unroll
    for (int r = 0; r < OUT_D; r++) atomicAdd(&lg[r], acc[r]);
    __syncthreads();
    if (tid == 0) {
        float l[OUT_D];
        float m = -1e30f;
        for (int r = 0; r < OUT_D; r++) {
            l[r] = lg[r] + b_o[r];
            m = fmaxf(m, l[r]);
        }
        float se = 0.0f;
        for (int r = 0; r < OUT_D; r++) se += expf(l[r] - m);
        float lse = m + logf(se);
        for (int r = 0; r < OUT_D; r++) out[HID + r] = l[r] - lse;
    }
}

extern "C" void kernel_launch(void* const* d_in, const int* in_sizes, int n_in,
                              void* d_out, int out_size, void* d_ws, size_t ws_size,
                              hipStream_t stream) {
    const float* x    = (const float*)d_in[0];
    const float* h0   = (const float*)d_in[1];
    const float* memC = (const float*)d_in[2];
    const float* addrR= (const float*)d_in[3];
    const float* W_q  = (const float*)d_in[4];
    const float* b_q  = (const float*)d_in[5];
    const float* u_s  = (const float*)d_in[6];
    const float* b_s  = (const float*)d_in[7];
    const float* u_l  = (const float*)d_in[8];
    const float* b_l  = (const float*)d_in[9];
    const float* W_e  = (const float*)d_in[10];
    const float* b_e  = (const float*)d_in[11];
    const float* W_ch = (const float*)d_in[12];
    const float* W_ci = (const float*)d_in[13];
    const float* b_c  = (const float*)d_in[14];
    const float* W_ih = (const float*)d_in[15];
    const float* W_hh = (const float*)d_in[16];
    const float* b_ih = (const float*)d_in[17];
    const float* b_hh = (const float*)d_in[18];
    const float* W_o  = (const float*)d_in[19];
    const float* b_o  = (const float*)d_in[20];
    // d_in[21] = num_addressing_steps = 8 (baked in; graph must be static anyway)

    const size_t MEMF = (size_t)N_LOC * CONTENT;
    // small-region layout (floats)
    const size_t SM_ADDRSQ = 0;
    const size_t SM_S      = SM_ADDRSQ + N_LOC;
    const size_t SM_EMA    = SM_S + N_LOC;
    const size_t SM_W      = SM_EMA + N_LOC;
    const size_t SM_QUERY  = SM_W + N_LOC;
    const size_t SM_READ   = SM_QUERY + OVERALL;
    const size_t SM_ER     = SM_READ + OVERALL;
    const size_t SM_CAND   = SM_ER + CONTENT;
    const size_t SM_HA     = SM_CAND + CONTENT;
    const size_t SM_HB     = SM_HA + HID;
    const size_t SM_SLOTS  = SM_HB + HID;
    const size_t SM_TOT    = SM_SLOTS + 64;

    float* wsF = (float*)d_ws;
    bool useWs = ws_size >= (MEMF + SM_TOT) * sizeof(float);
    // Fallback: if ws too small for the mem copy, update memory_contents in place
    // (harness restores d_in from pristine before every launch).
    float* memBuf = useWs ? wsF : (float*)d_in[2];
    float* sb     = useWs ? (wsF + MEMF) : wsF;

    float* addrsq  = sb + SM_ADDRSQ;
    float* sArr    = sb + SM_S;
    float* ema     = sb + SM_EMA;
    float* wArr    = sb + SM_W;
    float* query   = sb + SM_QUERY;
    float* reading = sb + SM_READ;
    float* erase   = sb + SM_ER;
    float* cand    = sb + SM_CAND;
    float* hA      = sb + SM_HA;
    float* hB      = sb + SM_HB;
    float* slots   = sb + SM_SLOTS;

    k_init<<<2048, 256, 0, stream>>>(addrR, addrsq, ema, slots);
    // query_0 / beta_0 / gamma_0 inputs from h0
    k_small<<<(578 + 3) / 4, 256, 0, stream>>>(W_e, b_e, W_ch, W_ci, b_c, W_q, b_q,
                                               u_s, u_l, x, h0,
                                               erase, cand, query, slots + 0, 0);
    const float* hcur = h0;
    for (int t = 0; t < NSTEPS; t++) {
        float* slots_t = slots + 8 * t;
        const float* memIn = (useWs && t <= 1) ? memC : memBuf;
        int upd = (t > 0) ? 1 : 0;
        k_passA<<<1024, 256, 0, stream>>>(memIn, memBuf, upd, addrR, query, wArr,
                                          erase, cand, addrsq, sArr, ema, reading,
                                          slots_t, b_s, b_l, slots_t + 3);
        const float* memB = (useWs && t == 0) ? memC : memBuf;
        k_passB<<<512, 256, 0, stream>>>(memB, addrR, sArr, slots_t + 3, wArr, reading);
        float* hn = (t & 1) ? hB : hA;
        k_gru<<<256, 256, 0, stream>>>(W_ih, W_hh, b_ih, b_hh, x, reading, hcur, hn);
        if (t < NSTEPS - 1) {
            k_small<<<(2 * CONTENT + 578 + 3) / 4, 256, 0, stream>>>(
                W_e, b_e, W_ch, W_ci, b_c, W_q, b_q, u_s, u_l, x, hn,
                erase, cand, query, slots + 8 * (t + 1), CONTENT);
        }
        hcur = hn;
    }
    k_out<<<1, 256, 0, stream>>>(W_o, b_o, hcur, (float*)d_out);
}

// Round 3
// 677.653 us; speedup vs baseline: 1.3419x; 1.3419x over previous
//
#include <hip/hip_runtime.h>
#include <math.h>

#define N_LOC 32768
#define CONTENT 512
#define ADDR_D 64
#define HID 1024
#define IN_D 256
#define OUT_D 10
#define OVERALL 576
#define GRU_IN 832
#define EPS_C 1e-7f
#define NSTEPS 8

#define NBLK_P 1024
#define NWAVE_P (NBLK_P * 4)

__device__ __forceinline__ float wred(float v) {
    #pragma unroll
    for (int m = 32; m; m >>= 1) v += __shfl_xor(v, m, 64);
    return v;
}
__device__ __forceinline__ float sigm(float x) { return 1.0f / (1.0f + expf(-x)); }
__device__ __forceinline__ float dot4(float4 a, float4 b) {
    return a.x * b.x + a.y * b.y + a.z * b.z + a.w * b.w;
}

// ---------------- init: addr row norms^2, zero ema/reading/slots ----------------
__global__ __launch_bounds__(256) void k_init(const float* __restrict__ addrRows,
                                              float* __restrict__ addrsq,
                                              float* __restrict__ ema,
                                              float* __restrict__ reading,
                                              float* __restrict__ slots) {
    int tid = threadIdx.x, wid = tid >> 6, lane = tid & 63;
    int gid = blockIdx.x * 256 + tid;
    if (gid < N_LOC) ema[gid] = 0.0f;
    if (gid < NSTEPS * OVERALL) reading[gid] = 0.0f;
    if (gid < NSTEPS * 8) slots[gid] = 0.0f;
    for (int i = blockIdx.x * 4 + wid; i < N_LOC; i += gridDim.x * 4) {
        float a = addrRows[(size_t)i * ADDR_D + lane];
        float sq = wred(a * a);
        if (lane == 0) addrsq[i] = sq;
    }
}

// ---------------- small matvecs: erase, cand, query, u_s.h, u_l.h (float4) ----------------
__global__ __launch_bounds__(256) void k_small(
    const float* __restrict__ W_e, const float* __restrict__ b_e,
    const float* __restrict__ W_ch, const float* __restrict__ W_ci, const float* __restrict__ b_c,
    const float* __restrict__ W_q, const float* __restrict__ b_q,
    const float* __restrict__ u_s, const float* __restrict__ u_l,
    const float* __restrict__ x, const float* __restrict__ h,
    float* __restrict__ erase, float* __restrict__ cand, float* __restrict__ query,
    float* __restrict__ slots_t, int doEC) {
    int tid = threadIdx.x, wid = tid >> 6, lane = tid & 63;
    int t = blockIdx.x * 4 + wid;
    const int base = doEC ? 2 * CONTENT : 0;
    const float4* h4 = (const float4*)h;
    const float4* x4 = (const float4*)x;
    if (doEC && t < CONTENT) {
        const float4* row = (const float4*)(W_e + (size_t)t * HID);
        float d = 0.0f;
        #pragma unroll
        for (int i = 0; i < 4; i++) d += dot4(row[lane + 64 * i], h4[lane + 64 * i]);
        d = wred(d);
        if (lane == 0) erase[t] = sigm(d + b_e[t]);
    } else if (doEC && t < 2 * CONTENT) {
        int r = t - CONTENT;
        const float4* row = (const float4*)(W_ch + (size_t)r * HID);
        float d = 0.0f;
        #pragma unroll
        for (int i = 0; i < 4; i++) d += dot4(row[lane + 64 * i], h4[lane + 64 * i]);
        const float4* row2 = (const float4*)(W_ci + (size_t)r * IN_D);
        d += dot4(row2[lane], x4[lane]);
        d = wred(d);
        if (lane == 0) cand[r] = fmaxf(d + b_c[r], 0.0f);
    } else if (t >= base && t < base + OVERALL) {
        int r = t - base;
        const float4* row = (const float4*)(W_q + (size_t)r * HID);
        float d = 0.0f;
        #pragma unroll
        for (int i = 0; i < 4; i++) d += dot4(row[lane + 64 * i], h4[lane + 64 * i]);
        d = wred(d);
        if (lane == 0) {
            float q = d + b_q[r];
            query[r] = q;
            atomicAdd(slots_t + 0, q * q);
        }
    } else if (t == base + OVERALL) {
        const float4* us4 = (const float4*)u_s;
        float d = 0.0f;
        #pragma unroll
        for (int i = 0; i < 4; i++) d += dot4(us4[lane + 64 * i], h4[lane + 64 * i]);
        d = wred(d);
        if (lane == 0) atomicAdd(slots_t + 1, d);
    } else if (t == base + OVERALL + 1) {
        const float4* ul4 = (const float4*)u_l;
        float d = 0.0f;
        #pragma unroll
        for (int i = 0; i < 4; i++) d += dot4(ul4[lane + 64 * i], h4[lane + 64 * i]);
        d = wred(d);
        if (lane == 0) atomicAdd(slots_t + 2, d);
    }
}

// ---------------- fused pass: lazy update + dots + sim + exp + reading numerator ----------------
__global__ __launch_bounds__(256) void k_passAB(
    const float* __restrict__ memIn, float* __restrict__ memOut,
    int doUpdate, int doStore,
    const float* __restrict__ addrRows, const float* __restrict__ query,
    const float* __restrict__ erase, const float* __restrict__ cand,
    const float* __restrict__ addrsq, float* __restrict__ ema,
    float* __restrict__ exp_s, float* __restrict__ reading,
    const float* __restrict__ slots_t, const float* __restrict__ ssum_prev,
    const float* __restrict__ b_sh, const float* __restrict__ b_lr,
    float* __restrict__ ssum_out) {
    int tid = threadIdx.x, wid = tid >> 6, lane = tid & 63;
    int gw = blockIdx.x * 4 + wid;

    __shared__ float lred[OVERALL];
    __shared__ float lsum4[4];
    for (int c = tid; c < OVERALL; c += 256) lred[c] = 0.0f;

    const float qnorm = sqrtf(slots_t[0]);
    const float bs = slots_t[1] + b_sh[0];
    const float beta = (bs > 20.0f ? bs : log1pf(expf(bs))) + 1.0f;
    const float gamma = sigm(slots_t[2] + b_lr[0]);

    const float4 q0 = *(const float4*)(query + 4 * lane);
    const float4 q1 = *(const float4*)(query + 256 + 4 * lane);
    const float qa = query[512 + lane];
    float4 e0 = {0,0,0,0}, e1 = {0,0,0,0}, c0 = {0,0,0,0}, c1 = {0,0,0,0};
    float invp = 0.0f;
    if (doUpdate) {
        e0 = *(const float4*)(erase + 4 * lane);
        e1 = *(const float4*)(erase + 256 + 4 * lane);
        c0 = *(const float4*)(cand + 4 * lane);
        c1 = *(const float4*)(cand + 256 + 4 * lane);
        invp = 1.0f / ssum_prev[0];
    }
    __syncthreads();

    float4 racc0 = {0,0,0,0}, racc1 = {0,0,0,0};
    float racca = 0.0f, lsum = 0.0f;

    for (int i = gw; i < N_LOC; i += NWAVE_P) {
        const float4* rowp = (const float4*)(memIn + (size_t)i * CONTENT);
        float4 m0 = rowp[lane];
        float4 m1 = rowp[64 + lane];
        float av = addrRows[(size_t)i * ADDR_D + lane];
        if (doUpdate) {
            float wv = exp_s[i] * invp;
            m0.x = m0.x * (1.0f - wv * e0.x) + wv * c0.x;
            m0.y = m0.y * (1.0f - wv * e0.y) + wv * c0.y;
            m0.z = m0.z * (1.0f - wv * e0.z) + wv * c0.z;
            m0.w = m0.w * (1.0f - wv * e0.w) + wv * c0.w;
            m1.x = m1.x * (1.0f - wv * e1.x) + wv * c1.x;
            m1.y = m1.y * (1.0f - wv * e1.y) + wv * c1.y;
            m1.z = m1.z * (1.0f - wv * e1.z) + wv * c1.z;
            m1.w = m1.w * (1.0f - wv * e1.w) + wv * c1.w;
            if (doStore) {
                float4* op = (float4*)(memOut + (size_t)i * CONTENT);
                op[lane] = m0;
                op[64 + lane] = m1;
            }
        }
        float d = dot4(m0, q0) + dot4(m1, q1) + av * qa;
        float sq = dot4(m0, m0) + dot4(m1, m1);
        d = wred(d);
        sq = wred(sq);
        float rn = sqrtf(sq + addrsq[i]);
        float sim = beta * d / (rn * qnorm + EPS_C);
        float eo = ema[i];
        float es = expf(sim - gamma * eo);
        if (lane == 0) {
            ema[i] = 0.1f * eo + 0.9f * sim;
            exp_s[i] = es;
        }
        lsum += es;
        racc0.x += es * m0.x; racc0.y += es * m0.y; racc0.z += es * m0.z; racc0.w += es * m0.w;
        racc1.x += es * m1.x; racc1.y += es * m1.y; racc1.z += es * m1.z; racc1.w += es * m1.w;
        racca += es * av;
    }
    atomicAdd(&lred[4 * lane + 0], racc0.x);
    atomicAdd(&lred[4 * lane + 1], racc0.y);
    atomicAdd(&lred[4 * lane + 2], racc0.z);
    atomicAdd(&lred[4 * lane + 3], racc0.w);
    atomicAdd(&lred[256 + 4 * lane + 0], racc1.x);
    atomicAdd(&lred[256 + 4 * lane + 1], racc1.y);
    atomicAdd(&lred[256 + 4 * lane + 2], racc1.z);
    atomicAdd(&lred[256 + 4 * lane + 3], racc1.w);
    atomicAdd(&lred[512 + lane], racca);
    if (lane == 0) lsum4[wid] = lsum;
    __syncthreads();
    for (int c = tid; c < OVERALL; c += 256) atomicAdd(reading + c, lred[c]);
    if (tid == 0) atomicAdd(ssum_out, lsum4[0] + lsum4[1] + lsum4[2] + lsum4[3]);
}

// ---------------- GRU: one wave per hidden unit (float4) ----------------
__global__ __launch_bounds__(256) void k_gru(
    const float* __restrict__ W_ih, const float* __restrict__ W_hh,
    const float* __restrict__ b_ih, const float* __restrict__ b_hh,
    const float* __restrict__ x, const float* __restrict__ reading,
    const float* __restrict__ ssum,
    const float* __restrict__ hcur, float* __restrict__ hnew) {
    int tid = threadIdx.x, wid = tid >> 6, lane = tid & 63;
    int k = blockIdx.x * 4 + wid;
    if (k >= HID) return;
    const float invs = 1.0f / ssum[0];
    const float4* x4 = (const float4*)x;
    const float4* r4 = (const float4*)reading;
    const float4* h4 = (const float4*)hcur;
    const float4* Wi0 = (const float4*)(W_ih + (size_t)k * GRU_IN);
    const float4* Wi1 = (const float4*)(W_ih + (size_t)(k + HID) * GRU_IN);
    const float4* Wi2 = (const float4*)(W_ih + (size_t)(k + 2 * HID) * GRU_IN);
    float gi0 = 0, gi1 = 0, gi2 = 0;
    {   // floats 0..255 = x
        float4 v = x4[lane];
        gi0 += dot4(Wi0[lane], v); gi1 += dot4(Wi1[lane], v); gi2 += dot4(Wi2[lane], v);
    }
    #pragma unroll
    for (int i = 0; i < 2; i++) {  // floats 256..767 = reading[0..511]
        float4 v = r4[lane + 64 * i];
        v.x *= invs; v.y *= invs; v.z *= invs; v.w *= invs;
        gi0 += dot4(Wi0[64 + lane + 64 * i], v);
        gi1 += dot4(Wi1[64 + lane + 64 * i], v);
        gi2 += dot4(Wi2[64 + lane + 64 * i], v);
    }
    {   // floats 768..831 = reading[512..575]
        int j = 768 + lane;
        float v = reading[512 + lane] * invs;
        gi0 += W_ih[(size_t)k * GRU_IN + j] * v;
        gi1 += W_ih[(size_t)(k + HID) * GRU_IN + j] * v;
        gi2 += W_ih[(size_t)(k + 2 * HID) * GRU_IN + j] * v;
    }
    const float4* Wh0 = (const float4*)(W_hh + (size_t)k * HID);
    const float4* Wh1 = (const float4*)(W_hh + (size_t)(k + HID) * HID);
    const float4* Wh2 = (const float4*)(W_hh + (size_t)(k + 2 * HID) * HID);
    float gh0 = 0, gh1 = 0, gh2 = 0;
    #pragma unroll
    for (int i = 0; i < 4; i++) {
        float4 v = h4[lane + 64 * i];
        gh0 += dot4(Wh0[lane + 64 * i], v);
        gh1 += dot4(Wh1[lane + 64 * i], v);
        gh2 += dot4(Wh2[lane + 64 * i], v);
    }
    gi0 = wred(gi0); gi1 = wred(gi1); gi2 = wred(gi2);
    gh0 = wred(gh0); gh1 = wred(gh1); gh2 = wred(gh2);
    if (lane == 0) {
        float r = sigm(gi0 + b_ih[k] + gh0 + b_hh[k]);
        float z = sigm(gi1 + b_ih[HID + k] + gh1 + b_hh[HID + k]);
        float n = tanhf(gi2 + b_ih[2 * HID + k] + r * (gh2 + b_hh[2 * HID + k]));
        hnew[k] = (1.0f - z) * n + z * hcur[k];
    }
}

// ---------------- output: copy h, logits + log_softmax ----------------
__global__ __launch_bounds__(256) void k_out(const float* __restrict__ W_o,
                                             const float* __restrict__ b_o,
                                             const float* __restrict__ h,
                                             float* __restrict__ out) {
    int tid = threadIdx.x, wid = tid >> 6, lane = tid & 63;
    __shared__ float lg[OUT_D];
    for (int j = tid; j < HID; j += 256) out[j] = h[j];
    const float4* h4 = (const float4*)h;
    for (int u = wid; u < OUT_D; u += 4) {
        const float4* row = (const float4*)(W_o + (size_t)u * HID);
        float d = 0.0f;
        #pragma unroll
        for (int i = 0; i < 4; i++) d += dot4(row[lane + 64 * i], h4[lane + 64 * i]);
        d = wred(d);
        if (lane == 0) lg[u] = d + b_o[u];
    }
    __syncthreads();
    if (tid == 0) {
        float m = -1e30f;
        for (int u = 0; u < OUT_D; u++) m = fmaxf(m, lg[u]);
        float se = 0.0f;
        for (int u = 0; u < OUT_D; u++) se += expf(lg[u] - m);
        float lse = m + logf(se);
        for (int u = 0; u < OUT_D; u++) out[HID + u] = lg[u] - lse;
    }
}

extern "C" void kernel_launch(void* const* d_in, const int* in_sizes, int n_in,
                              void* d_out, int out_size, void* d_ws, size_t ws_size,
                              hipStream_t stream) {
    const float* x    = (const float*)d_in[0];
    const float* h0   = (const float*)d_in[1];
    const float* memC = (const float*)d_in[2];
    const float* addrR= (const float*)d_in[3];
    const float* W_q  = (const float*)d_in[4];
    const float* b_q  = (const float*)d_in[5];
    const float* u_s  = (const float*)d_in[6];
    const float* b_s  = (const float*)d_in[7];
    const float* u_l  = (const float*)d_in[8];
    const float* b_l  = (const float*)d_in[9];
    const float* W_e  = (const float*)d_in[10];
    const float* b_e  = (const float*)d_in[11];
    const float* W_ch = (const float*)d_in[12];
    const float* W_ci = (const float*)d_in[13];
    const float* b_c  = (const float*)d_in[14];
    const float* W_ih = (const float*)d_in[15];
    const float* W_hh = (const float*)d_in[16];
    const float* b_ih = (const float*)d_in[17];
    const float* b_hh = (const float*)d_in[18];
    const float* W_o  = (const float*)d_in[19];
    const float* b_o  = (const float*)d_in[20];
    // d_in[21] = num_addressing_steps = 8 (baked in; graph is static anyway)

    const size_t MEMF = (size_t)N_LOC * CONTENT;
    // small-region layout (floats, all offsets multiple of 16)
    const size_t SM_ADDRSQ = 0;
    const size_t SM_EXPS   = SM_ADDRSQ + N_LOC;
    const size_t SM_EMA    = SM_EXPS + N_LOC;
    const size_t SM_READ   = SM_EMA + N_LOC;              // NSTEPS*OVERALL
    const size_t SM_QUERY  = SM_READ + NSTEPS * OVERALL;  // NSTEPS*OVERALL
    const size_t SM_ER     = SM_QUERY + NSTEPS * OVERALL; // NSTEPS*CONTENT
    const size_t SM_CAND   = SM_ER + NSTEPS * CONTENT;
    const size_t SM_H      = SM_CAND + NSTEPS * CONTENT;  // (NSTEPS+1)*HID
    const size_t SM_SLOTS  = SM_H + (NSTEPS + 1) * HID;
    const size_t SM_TOT    = SM_SLOTS + NSTEPS * 8;

    float* wsF = (float*)d_ws;
    bool useWs = ws_size >= (MEMF + SM_TOT) * sizeof(float);
    // If ws too small, update memory in place (harness restores d_in each launch).
    float* memBuf = useWs ? wsF : (float*)d_in[2];
    float* sb     = useWs ? (wsF + MEMF) : wsF;

    float* addrsq  = sb + SM_ADDRSQ;
    float* exp_s   = sb + SM_EXPS;
    float* ema     = sb + SM_EMA;
    float* reading = sb + SM_READ;
    float* query   = sb + SM_QUERY;
    float* erase   = sb + SM_ER;
    float* cand    = sb + SM_CAND;
    float* H       = sb + SM_H;
    float* slots   = sb + SM_SLOTS;

    k_init<<<2048, 256, 0, stream>>>(addrR, addrsq, ema, reading, slots);
    k_small<<<(OVERALL + 2 + 3) / 4, 256, 0, stream>>>(
        W_e, b_e, W_ch, W_ci, b_c, W_q, b_q, u_s, u_l, x, h0,
        erase, cand, query, slots, 0);

    const float* hcur = h0;
    for (int t = 0; t < NSTEPS; t++) {
        float* slt = slots + t * 8;
        int doUpd = (t > 0) ? 1 : 0;
        int doStore = (t >= 1 && t <= NSTEPS - 2) ? 1 : 0;
        const float* memIn = (useWs && t <= 1) ? memC : memBuf;
        k_passAB<<<NBLK_P, 256, 0, stream>>>(
            memIn, memBuf, doUpd, doStore, addrR,
            query + t * OVERALL,
            erase + (t > 0 ? (t - 1) : 0) * CONTENT,
            cand + (t > 0 ? (t - 1) : 0) * CONTENT,
            addrsq, ema, exp_s, reading + t * OVERALL,
            slt, (t > 0 ? slots + (t - 1) * 8 + 3 : slt), b_s, b_l, slt + 3);
        float* hn = H + (t + 1) * HID;
        k_gru<<<HID / 4, 256, 0, stream>>>(W_ih, W_hh, b_ih, b_hh, x,
                                           reading + t * OVERALL, slt + 3, hcur, hn);
        if (t < NSTEPS - 1) {
            k_small<<<(2 * CONTENT + OVERALL + 2 + 3) / 4, 256, 0, stream>>>(
                W_e, b_e, W_ch, W_ci, b_c, W_q, b_q, u_s, u_l, x, hn,
                erase + t * CONTENT, cand + t * CONTENT,
                query + (t + 1) * OVERALL, slots + (t + 1) * 8, 1);
        }
        hcur = hn;
    }
    k_out<<<1, 256, 0, stream>>>(W_o, b_o, hcur, (float*)d_out);
}